// Round 8
// baseline (789.746 us; speedup 1.0000x reference)
//
#include <hip/hip_runtime.h>
#include <hip/hip_bf16.h>
#include <hip/hip_fp16.h>

// ---------------------------------------------------------------------------
// GNN: h = relu(GCN(x)); h = relu(GAT(h)); h = relu(GCN(h)); h = relu(GAT(h));
//      z = h @ Wo + bo.  Outputs: [h (N*128), z (N*64)] fp32.
// R16: R15's XCD slicing VERIFIED locality (FETCH 85->52MB) but its 2-lane
//     serial loop starved MLP (VALU 9.5%, 115us). This round keeps the
//     mechanism (real XCC id via s_getreg, per-slice cursors, exactly-once,
//     stealing) and restores the R9 wave-gather shape inside it:
//     4 slices x 32 feats (3.2MB/slice < 4MB L2, 64B/edge gather); wave =
//     16 edge-groups x 4 feature-lanes; 64-edge blocks; 16 edges in flight
//     per u-step; shfl_xor tree over groups. Edge stream read 4x (was 8x).
//     GEMM slice-major I/O: A-read slice=ks, C-write slice=nt>>1.
//     k_wgcn/k_alpha (hoisted packed (src,w), bit-identical softmax), build,
//     GEMM core, fp16-h chain unchanged from R14/R15.
// ---------------------------------------------------------------------------

#define WAVE 64
#define BK 256        // nodes per bucket
#define CHUNK 4096    // edges per k_bscatter block
#define NSL 4         // feature slices (32 fp16 = 64 B per node per slice)
#define CURSTRIDE 16  // ints between cursors (64 B, own cacheline)
#define NCHUNK 64     // nodes per cursor grab

typedef _Float16 f16x8 __attribute__((ext_vector_type(8)));
typedef float f32x4 __attribute__((ext_vector_type(4)));

// ------------------------------ graph build --------------------------------
// edge e in [0,E): (s,d) = (ei[e], ei[E+e]); e in [E,Et): self-loop (e-E,e-E)
// Merged with weight convert. Wt layout: [0]W1 [16384]Wg1 [32768]W2 [49152]Wg2
// [65536]Wo, fragment-major: elem ((nt*4+ks)*64+lane)*8+j = W[k][n],
// n = nt*16+(lane&15), k = ks*32+(lane>>4)*8+j.

__global__ __launch_bounds__(256) void k_bhist_wcvt(
    const int* __restrict__ ei, int* __restrict__ bcnt, int E, int Et, int nbuck,
    const float* __restrict__ W1, const float* __restrict__ Wg1,
    const float* __restrict__ W2, const float* __restrict__ Wg2,
    const float* __restrict__ Wo, __half* __restrict__ Wt) {
    __shared__ int hist[256];
    int tid = threadIdx.x;
    if (tid < nbuck) hist[tid] = 0;
    __syncthreads();
    for (int e = blockIdx.x * 256 + tid; e < Et; e += gridDim.x * 256) {
        int d = (e < E) ? ei[E + e] : (e - E);
        atomicAdd(&hist[d >> 8], 1);
    }
    __syncthreads();
    if (tid < nbuck && hist[tid] > 0) atomicAdd(&bcnt[tid], hist[tid]);

    int i = blockIdx.x * 256 + tid;
    if (i < 65536) {
        int w = i >> 14;
        int j = i & 16383;
        int nt = j >> 11, ks = (j >> 9) & 3, lane = (j >> 3) & 63, jj = j & 7;
        int n = nt * 16 + (lane & 15);
        int k = ks * 32 + (lane >> 4) * 8 + jj;
        const float* W = (w == 0) ? W1 : (w == 1) ? Wg1 : (w == 2) ? W2 : Wg2;
        Wt[i] = __float2half(W[k * 128 + n]);
    } else if (i < 73728) {
        int j = i - 65536;                    // 8192: Wo is 128x64 -> NT=4
        int nt = j >> 11, ks = (j >> 9) & 3, lane = (j >> 3) & 63, jj = j & 7;
        int n = nt * 16 + (lane & 15);
        int k = ks * 32 + (lane >> 4) * 8 + jj;
        Wt[65536 + j] = __float2half(Wo[k * 64 + n]);
    }
}

__global__ void k_bscan(const int* __restrict__ bcnt, int* __restrict__ bbase,
                        int* __restrict__ bcur, int nbuck) {
    __shared__ int tmp[256];
    int tid = threadIdx.x;
    int v = (tid < nbuck) ? bcnt[tid] : 0;
    tmp[tid] = v;
    __syncthreads();
    for (int off = 1; off < 256; off <<= 1) {
        int t = (tid >= off) ? tmp[tid - off] : 0;
        __syncthreads();
        tmp[tid] += t;
        __syncthreads();
    }
    if (tid < nbuck) {
        int excl = tmp[tid] - v;
        bbase[tid] = excl;
        bcur[tid] = excl;
        if (tid == nbuck - 1) bbase[nbuck] = tmp[tid];
    }
}

__global__ __launch_bounds__(256) void k_bscatter(
    const int* __restrict__ ei, int* __restrict__ bcur,
    int2* __restrict__ ebuf, int E, int Et, int nbuck) {
    __shared__ int hist[256];
    __shared__ int base[256];
    __shared__ int off[256];
    constexpr int PT = CHUNK / 256;   // 16 edges per thread
    int tid = threadIdx.x;
    int cb = blockIdx.x * CHUNK;
    if (tid < nbuck) { hist[tid] = 0; off[tid] = 0; }
    __syncthreads();

    int sv[PT], dv[PT];
#pragma unroll
    for (int i = 0; i < PT; ++i) {
        int e = cb + i * 256 + tid;
        int s = 0, d = -1;
        if (e < Et) {
            if (e < E) { s = ei[e]; d = ei[E + e]; }
            else       { s = d = e - E; }
            atomicAdd(&hist[d >> 8], 1);
        }
        sv[i] = s; dv[i] = d;
    }
    __syncthreads();
    if (tid < nbuck && hist[tid] > 0)
        base[tid] = atomicAdd(&bcur[tid], hist[tid]);
    __syncthreads();
#pragma unroll
    for (int i = 0; i < PT; ++i) {
        if (dv[i] >= 0) {
            int b = dv[i] >> 8;
            int pos = base[b] + atomicAdd(&off[b], 1);
            ebuf[pos] = make_int2(sv[i], dv[i]);
        }
    }
}

__global__ __launch_bounds__(256) void k_csr(
    const int2* __restrict__ ebuf, const int* __restrict__ bbase,
    int* __restrict__ rowp, float* __restrict__ inv, int* __restrict__ esrc,
    int Nn, int Et) {
    __shared__ int hist[256];
    __shared__ int scan[256];
    __shared__ int cur[256];
    int tid = threadIdx.x;
    int b = blockIdx.x;
    int bb = bbase[b], cnt = bbase[b + 1] - bb;
    hist[tid] = 0;
    __syncthreads();
    for (int t = tid; t < cnt; t += 256)
        atomicAdd(&hist[ebuf[bb + t].y & 255], 1);
    __syncthreads();
    int v = hist[tid];
    scan[tid] = v;
    __syncthreads();
    for (int o = 1; o < 256; o <<= 1) {
        int t = (tid >= o) ? scan[tid - o] : 0;
        __syncthreads();
        scan[tid] += t;
        __syncthreads();
    }
    int excl = scan[tid] - v;
    int node = b * BK + tid;
    if (node < Nn) {
        rowp[node] = bb + excl;
        inv[node] = rsqrtf((float)v);
    }
    cur[tid] = excl;
    if (b == 0 && tid == 0) rowp[Nn] = Et;
    __syncthreads();
    for (int t = tid; t < cnt; t += 256) {
        int2 e = ebuf[bb + t];
        int pos = bb + atomicAdd(&cur[e.y & 255], 1);
        esrc[pos] = e.x;
    }
}

// ------------------------- per-edge weight kernels -------------------------
// R10-verified. ew[e] = (src_id, weight-as-int-bits). One wave per node.

__global__ __launch_bounds__(256) void k_wgcn(
    const int* __restrict__ rowp, const int* __restrict__ esrc,
    const float* __restrict__ inv, int2* __restrict__ ew, int Nn) {
    int gid = blockIdx.x * 256 + threadIdx.x;
    int n = gid >> 6, lane = gid & 63;
    if (n >= Nn) return;
    int beg = rowp[n], end = rowp[n + 1];
    float invd = inv[n];
    for (int e = beg + lane; e < end; e += WAVE) {
        int sid = esrc[e];
        ew[e] = make_int2(sid, __float_as_int(invd * inv[sid]));
    }
}

__global__ __launch_bounds__(256) void k_alpha(
    const int* __restrict__ rowp, const int* __restrict__ esrc,
    const float* __restrict__ as_, const float* __restrict__ ad_,
    int2* __restrict__ ew, int Nn) {
    int gid = blockIdx.x * 256 + threadIdx.x;
    int n = gid >> 6, lane = gid & 63;
    if (n >= Nn) return;
    int beg = rowp[n], end = rowp[n + 1];
    int deg = end - beg;
    float adn = ad_[n];

    if (deg <= WAVE) {
        // fast path (deg<=64, ~all nodes) — same math as R6-R15 fused path
        bool valid = (lane < deg);
        int sid = 0;
        float v = -1e30f;
        if (valid) {
            sid = esrc[beg + lane];
            float t = as_[sid] + adn;
            v = (t > 0.f) ? t : 0.2f * t;
        }
        float m = v;
#pragma unroll
        for (int off = 32; off > 0; off >>= 1) m = fmaxf(m, __shfl_xor(m, off));
        float ex = valid ? __expf(v - m) : 0.f;
        float ssum = ex;
#pragma unroll
        for (int off = 32; off > 0; off >>= 1) ssum += __shfl_xor(ssum, off);
        float wgt = ex * (1.f / ssum);
        if (valid) ew[beg + lane] = make_int2(sid, __float_as_int(wgt));
    } else {
        // generic two-pass path (deg>64: essentially never at E/N=17)
        float m = -1e30f, ssum = 0.f;
        for (int e = beg + lane; e < end; e += WAVE) {
            float v = as_[esrc[e]] + adn;
            v = (v > 0.f) ? v : 0.2f * v;
            float mn = fmaxf(m, v);
            ssum = ssum * __expf(m - mn) + __expf(v - mn);
            m = mn;
        }
#pragma unroll
        for (int off = 32; off > 0; off >>= 1) {
            float mo = __shfl_xor(m, off);
            float so = __shfl_xor(ssum, off);
            float mn = fmaxf(m, mo);
            ssum = ssum * __expf(m - mn) + so * __expf(mo - mn);
            m = mn;
        }
        float rden = 1.f / ssum;
        for (int e = beg + lane; e < end; e += WAVE) {
            int sid = esrc[e];
            float v = as_[sid] + adn;
            v = (v > 0.f) ? v : 0.2f * v;
            ew[e] = make_int2(sid, __float_as_int(__expf(v - m) * rden));
        }
    }
}

// ------------------------------ MFMA GEMM ----------------------------------
// out[M x NC] = A(M x 128) @ W(fp16, fragment-major Wt); fp32 accum.
// A: fp32 node-major (ASLICE=false) or fp16 slice-major [4][M][32] (true;
// k = ks*32+quad*8+j -> slice = ks, offset quad*8: one coalesced 16B load).
// fp16 out (NC=128) written slice-major [4][M][32]: slice = nt>>1, within-
// slice col = (nt&1)*16+m16. fp32 out (NC=64, final z) node-major with bias.
// If asrc!=null, GAT alpha logits reduced from fp32 accumulators.

template <typename AT, bool ASLICE, int NC, typename OT>
__global__ __launch_bounds__(256) void gemm_mfma(
    const AT* __restrict__ A, const __half* __restrict__ Wt,
    const float* __restrict__ bias, OT* __restrict__ out,
    const float* __restrict__ asrc, const float* __restrict__ adst,
    float* __restrict__ alS, float* __restrict__ alD, int M) {
    constexpr int NT = NC / 16;
    __shared__ f16x8 Wl[NC * 16];             // NC*128 halfs, fragment-major
    const int tid = threadIdx.x;
    const int wv = tid >> 6, lane = tid & 63;
    const int m16 = lane & 15, quad = lane >> 4;

#pragma unroll
    for (int i = tid; i < NC * 16; i += 256)
        Wl[i] = ((const f16x8*)Wt)[i];
    __syncthreads();

    const int row0 = blockIdx.x * 64 + wv * 16;

    f16x8 af[4];
    {
        int row = row0 + m16;
        if (row > M - 1) row = M - 1;
        if constexpr (ASLICE) {
            const __half* ab = (const __half*)A;
#pragma unroll
            for (int ks = 0; ks < 4; ++ks)
                af[ks] = *(const f16x8*)(ab + ((size_t)ks * M + row) * 32
                                         + quad * 8);
        } else {
            const float* ap = (const float*)A + (size_t)row * 128 + quad * 8;
#pragma unroll
            for (int ks = 0; ks < 4; ++ks) {
                float4 lo = *(const float4*)(ap + ks * 32);
                float4 hi = *(const float4*)(ap + ks * 32 + 4);
                f16x8 v;
                v[0] = (_Float16)lo.x; v[1] = (_Float16)lo.y;
                v[2] = (_Float16)lo.z; v[3] = (_Float16)lo.w;
                v[4] = (_Float16)hi.x; v[5] = (_Float16)hi.y;
                v[6] = (_Float16)hi.z; v[7] = (_Float16)hi.w;
                af[ks] = v;
            }
        }
    }

    f32x4 acc[NT];
#pragma unroll
    for (int nt = 0; nt < NT; ++nt)
        acc[nt] = (f32x4){0.f, 0.f, 0.f, 0.f};

#pragma unroll
    for (int ks = 0; ks < 4; ++ks) {
#pragma unroll
        for (int nt = 0; nt < NT; ++nt) {
            f16x8 bf = Wl[(nt * 4 + ks) * 64 + lane];
            acc[nt] = __builtin_amdgcn_mfma_f32_16x16x32_f16(
                af[ks], bf, acc[nt], 0, 0, 0);
        }
    }

    // fused GAT alpha: s = xw.asrc, d = xw.adst per row (from fp32 accum)
    if (asrc) {
        float sa[NT], da[NT];
#pragma unroll
        for (int nt = 0; nt < NT; ++nt) {
            sa[nt] = asrc[nt * 16 + m16];
            da[nt] = adst[nt * 16 + m16];
        }
#pragma unroll
        for (int r = 0; r < 4; ++r) {
            float s = 0.f, d = 0.f;
#pragma unroll
            for (int nt = 0; nt < NT; ++nt) {
                s = fmaf(acc[nt][r], sa[nt], s);
                d = fmaf(acc[nt][r], da[nt], d);
            }
#pragma unroll
            for (int off = 8; off > 0; off >>= 1) {
                s += __shfl_xor(s, off);
                d += __shfl_xor(d, off);
            }
            int row = row0 + quad * 4 + r;
            if (m16 == 0 && row < M) { alS[row] = s; alD[row] = d; }
        }
    }

#pragma unroll
    for (int nt = 0; nt < NT; ++nt) {
#pragma unroll
        for (int r = 0; r < 4; ++r) {
            int row = row0 + quad * 4 + r;
            if (row < M) {
                float v = acc[nt][r];
                if constexpr (sizeof(OT) == 2) {
                    // slice-major [4][M][32]: slice = nt>>1
                    ((__half*)out)[(((size_t)(nt >> 1) * M + row) * 32)
                                   + (nt & 1) * 16 + m16] = __float2half(v);
                } else {
                    int col = nt * 16 + m16;
                    ((float*)out)[(size_t)row * NC + col] = v + bias[col];
                }
            }
        }
    }
}

// ---------------------- XCD-sliced weighted aggregation --------------------
// xs: [NSL][Nn][32] fp16 slice-major (3.2MB/slice -> fits 4MB XCD L2).
// Block reads its REAL XCD id (s_getreg HW_REG_XCC_ID), works slice=xcc&3
// first; per-slice atomic cursors guarantee exactly-once; stealing passes
// drain leftovers. R9 wave-gather shape inside: wave per node, lane =
// 16 edge-groups (g) x 4 feature-lanes (q); 64-edge blocks via ew[beg+lane];
// 16 edges x 64B in flight per u-step; shfl_xor tree over g at the end.
// INVARIANT: lanes >= cnt hold wgt==0, sid==0; all guards wave-uniform.
// OT=fp16: write slice-major (next GEMM reads it). OT=fp32: node-major outH.

template <typename OT>
__global__ __launch_bounds__(256) void k_agg_slice(
    const __half* __restrict__ xs, const int* __restrict__ rowp,
    const int2* __restrict__ ew, const float* __restrict__ bias,
    OT* __restrict__ out, int* __restrict__ cursor, int Nn) {
    __shared__ int chunk_sh;
    int xcc;
    asm volatile("s_getreg_b32 %0, hwreg(HW_REG_XCC_ID)" : "=s"(xcc));
    const int tid = threadIdx.x;
    const int wv = tid >> 6, lane = tid & 63;
    const int g = lane >> 2, q = lane & 3;   // 16 edge-groups x 4 f16x8 lanes

    for (int pass = 0; pass < NSL; ++pass) {
        const int slice = (xcc + pass) & (NSL - 1);
        int* curp = cursor + slice * CURSTRIDE;
        const __half* xsl = xs + (size_t)slice * Nn * 32 + q * 8;
        float b8[8];
        *(float4*)(b8)     = *(const float4*)(bias + slice * 32 + q * 8);
        *(float4*)(b8 + 4) = *(const float4*)(bias + slice * 32 + q * 8 + 4);

        for (;;) {
            if (tid == 0) {
                int c = *(volatile int*)curp;           // cheap probe
                chunk_sh = (c >= Nn) ? Nn : atomicAdd(curp, NCHUNK);
            }
            __syncthreads();
            const int n0 = chunk_sh;
            __syncthreads();
            if (n0 >= Nn) break;                        // block-uniform exit
            for (int i = wv; i < NCHUNK; i += 4) {
                const int n = n0 + i;                   // wave-uniform
                if (n >= Nn) break;
                int beg = rowp[n], end = rowp[n + 1];
                float acc[8] = {0.f,0.f,0.f,0.f,0.f,0.f,0.f,0.f};
                for (int ebase = beg; ebase < end; ebase += WAVE) {
                    int e = ebase + lane;
                    bool valid = (e < end);
                    int sid = 0;
                    float wgt = 0.f;
                    if (valid) {
                        int2 pp = ew[e];
                        sid = pp.x;
                        wgt = __int_as_float(pp.y);
                    }
                    int cnt = min(WAVE, end - ebase);   // wave-uniform
                    f16x8 xv[4];
                    float wu[4];
#pragma unroll
                    for (int u = 0; u < 4; ++u) {
                        if (u * 16 < cnt) {             // uniform guard
                            int idx = u * 16 + g;
                            int s = __shfl(sid, idx);
                            wu[u] = __shfl(wgt, idx);
                            xv[u] = *(const f16x8*)(xsl + (size_t)s * 32);
                        }
                    }
#pragma unroll
                    for (int u = 0; u < 4; ++u) {
                        if (u * 16 < cnt) {             // uniform guard
                            float w = wu[u];
#pragma unroll
                            for (int i2 = 0; i2 < 8; ++i2)
                                acc[i2] = fmaf(w, (float)xv[u][i2], acc[i2]);
                        }
                    }
                }
                // reduce over g (lane bits 2..5)
#pragma unroll
                for (int i2 = 0; i2 < 8; ++i2) {
                    acc[i2] += __shfl_xor(acc[i2], 4);
                    acc[i2] += __shfl_xor(acc[i2], 8);
                    acc[i2] += __shfl_xor(acc[i2], 16);
                    acc[i2] += __shfl_xor(acc[i2], 32);
                }
                if (g == 0) {                           // lanes 0..3 write
                    if constexpr (sizeof(OT) == 2) {
                        f16x8 hv;
#pragma unroll
                        for (int i2 = 0; i2 < 8; ++i2)
                            hv[i2] = (_Float16)fmaxf(acc[i2] + b8[i2], 0.f);
                        *(f16x8*)((__half*)out
                                  + ((size_t)slice * Nn + n) * 32 + q * 8) = hv;
                    } else {
                        float* op = (float*)out + (size_t)n * 128
                                    + slice * 32 + q * 8;
                        float4 r0, r1;
                        r0.x = fmaxf(acc[0] + b8[0], 0.f);
                        r0.y = fmaxf(acc[1] + b8[1], 0.f);
                        r0.z = fmaxf(acc[2] + b8[2], 0.f);
                        r0.w = fmaxf(acc[3] + b8[3], 0.f);
                        r1.x = fmaxf(acc[4] + b8[4], 0.f);
                        r1.y = fmaxf(acc[5] + b8[5], 0.f);
                        r1.z = fmaxf(acc[6] + b8[6], 0.f);
                        r1.w = fmaxf(acc[7] + b8[7], 0.f);
                        *(float4*)op = r0;
                        *(float4*)(op + 4) = r1;
                    }
                }
            }
        }
    }
}

// ------------------------------- launch ------------------------------------

extern "C" void kernel_launch(void* const* d_in, const int* in_sizes, int n_in,
                              void* d_out, int out_size, void* d_ws, size_t ws_size,
                              hipStream_t stream) {
    const float* x   = (const float*)d_in[0];
    const int*   ei  = (const int*)d_in[1];
    const float* W1  = (const float*)d_in[2];
    const float* b1  = (const float*)d_in[3];
    const float* Wg1 = (const float*)d_in[4];
    const float* as1 = (const float*)d_in[5];
    const float* ad1 = (const float*)d_in[6];
    const float* bg1 = (const float*)d_in[7];
    const float* W2  = (const float*)d_in[8];
    const float* b2  = (const float*)d_in[9];
    const float* Wg2 = (const float*)d_in[10];
    const float* as2 = (const float*)d_in[11];
    const float* ad2 = (const float*)d_in[12];
    const float* bg2 = (const float*)d_in[13];
    const float* Wo  = (const float*)d_in[14];
    const float* bo  = (const float*)d_in[15];

    const int Nn = in_sizes[0] / 128;
    const int E  = in_sizes[1] / 2;
    const int Et = E + Nn;
    const int H  = 128;
    const int nbuck = (Nn + BK - 1) / BK;   // 196

    float* outH = (float*)d_out;
    float* outZ = outH + (size_t)Nn * H;

    char* p = (char*)d_ws;
    auto carve = [&](size_t bytes) {
        char* r = p;
        p += (bytes + 255) & ~(size_t)255;
        return r;
    };
    __half* bufA = (__half*)carve((size_t)Nn * H * sizeof(__half));  // xw [4][Nn][32]
    __half* bufB = (__half*)carve((size_t)Nn * H * sizeof(__half));  // h  [4][Nn][32]
    __half* Wt   = (__half*)carve((size_t)73728 * sizeof(__half));   // fp16 W frags x5
    float* alS   = (float*)carve((size_t)Nn * sizeof(float));
    float* alD   = (float*)carve((size_t)Nn * sizeof(float));
    float* inv   = (float*)carve((size_t)Nn * sizeof(float));
    int*   rowp  = (int*)carve((size_t)(Nn + 1) * sizeof(int));
    int*   esrc  = (int*)carve((size_t)Et * sizeof(int));
    int2*  ebuf  = (int2*)carve((size_t)Et * sizeof(int2));
    int2*  ewg   = (int2*)carve((size_t)Et * sizeof(int2));          // GCN (src,w)
    // zero region: bcnt (nbuck) + 4 agg cursor sets (NSL slices x 16 ints)
    const int nCurInts = 4 * NSL * CURSTRIDE;                        // 256
    int*   zreg  = (int*)carve((size_t)(nbuck + nCurInts) * sizeof(int));
    int*   bcnt  = zreg;
    int*   curs  = zreg + nbuck;
    int*   bbase = (int*)carve((size_t)(nbuck + 1) * sizeof(int));
    int*   bcur  = (int*)carve((size_t)nbuck * sizeof(int));
    (void)ws_size; (void)n_in; (void)out_size;

    // ebuf is dead after k_csr; reuse as the GAT (src,alpha) buffer
    int2* ewa = ebuf;

    const int nodeWaves = (Nn * WAVE + 255) / 256;   // 12500: wave-per-node
    const int gemmB = (Nn + 63) / 64;                // 782
    const int scatB = (Et + CHUNK - 1) / CHUNK;      // 208
    const int aggB  = 1024;                          // 4 blocks/CU, self-scheduled

    // graph build (two-level bucket sort) + weight convert; zero cursors
    hipMemsetAsync(zreg, 0, (size_t)(nbuck + nCurInts) * sizeof(int), stream);
    k_bhist_wcvt<<<288, 256, 0, stream>>>(ei, bcnt, E, Et, nbuck,
                                          W1, Wg1, W2, Wg2, Wo, Wt);
    k_bscan<<<1, 256, 0, stream>>>(bcnt, bbase, bcur, nbuck);
    k_bscatter<<<scatB, 256, 0, stream>>>(ei, bcur, ebuf, E, Et, nbuck);
    k_csr<<<nbuck, 256, 0, stream>>>(ebuf, bbase, rowp, inv, esrc, Nn, Et);
    k_wgcn<<<nodeWaves, 256, 0, stream>>>(rowp, esrc, inv, ewg, Nn);

    // layer 1: GCN
    gemm_mfma<float, false, 128, __half><<<gemmB, 256, 0, stream>>>(
        x, Wt, nullptr, bufA, nullptr, nullptr, nullptr, nullptr, Nn);
    k_agg_slice<__half><<<aggB, 256, 0, stream>>>(
        bufA, rowp, ewg, b1, bufB, curs + 0 * NSL * CURSTRIDE, Nn);

    // layer 2: GAT
    gemm_mfma<__half, true, 128, __half><<<gemmB, 256, 0, stream>>>(
        bufB, Wt + 16384, nullptr, bufA, as1, ad1, alS, alD, Nn);
    k_alpha<<<nodeWaves, 256, 0, stream>>>(rowp, esrc, alS, alD, ewa, Nn);
    k_agg_slice<__half><<<aggB, 256, 0, stream>>>(
        bufA, rowp, ewa, bg1, bufB, curs + 1 * NSL * CURSTRIDE, Nn);

    // layer 3: GCN
    gemm_mfma<__half, true, 128, __half><<<gemmB, 256, 0, stream>>>(
        bufB, Wt + 32768, nullptr, bufA, nullptr, nullptr, nullptr, nullptr, Nn);
    k_agg_slice<__half><<<aggB, 256, 0, stream>>>(
        bufA, rowp, ewg, b2, bufB, curs + 2 * NSL * CURSTRIDE, Nn);

    // layer 4: GAT -> fp32 outH (required output h)
    gemm_mfma<__half, true, 128, __half><<<gemmB, 256, 0, stream>>>(
        bufB, Wt + 49152, nullptr, bufA, as2, ad2, alS, alD, Nn);
    k_alpha<<<nodeWaves, 256, 0, stream>>>(rowp, esrc, alS, alD, ewa, Nn);
    k_agg_slice<float><<<aggB, 256, 0, stream>>>(
        bufA, rowp, ewa, bg2, outH, curs + 3 * NSL * CURSTRIDE, Nn);

    // output layer: z = h @ Wo + bo
    gemm_mfma<float, false, 64, float><<<gemmB, 256, 0, stream>>>(
        outH, Wt + 65536, bo, outZ, nullptr, nullptr, nullptr, nullptr, Nn);
}

// Round 9
// 376.839 us; speedup vs baseline: 2.0957x; 2.0957x over previous
//
#include <hip/hip_runtime.h>
#include <hip/hip_bf16.h>
#include <hip/hip_fp16.h>

// ---------------------------------------------------------------------------
// GNN: h = relu(GCN(x)); h = relu(GAT(h)); h = relu(GCN(h)); h = relu(GAT(h));
//      z = h @ Wo + bo.  Outputs: [h (N*128), z (N*64)] fp32.
// R17: REVERT to R14 (best proven: 374.4us). The gather-restructuring arc is
//     closed as falsified: R10 (placement slices, flat), R11 (sorted sweep,
//     -19us), R15 (XCC slices + serial loop, 115us/agg), R16 (XCC slices +
//     wave gather, 145us/agg) all lost to this shape. R16's counters (FETCH
//     38MB yet 3x slower, HBM 440GB/s, VALU 30%) prove locality structures
//     trade latency/occupancy for traffic at a net loss here. R14 equilibrium:
//     one wave per node, full-row gather, ~47us/agg = ~85MB compulsory
//     per-XCD refill at the ~2.3TB/s random-granule service rate (R13 ILP
//     experiment confirmed service-rate-bound, not latency-bound).
//     Structure: R7 bucket-sort build; R9 frag-major MFMA GEMM (64 rows/blk);
//     R14 fp16 intermediate-h chain (bit-identical: next GEMM rounds to fp16
//     anyway); fused GAT-alpha in GEMM epilogue; wcvt merged into bhist.
// ---------------------------------------------------------------------------

#define WAVE 64
#define BK 256        // nodes per bucket
#define CHUNK 4096    // edges per k_bscatter block

typedef _Float16 f16x8 __attribute__((ext_vector_type(8)));
typedef float f32x4 __attribute__((ext_vector_type(4)));

// ------------------------------ graph build --------------------------------
// edge e in [0,E): (s,d) = (ei[e], ei[E+e]); e in [E,Et): self-loop (e-E,e-E)
// Merged with weight convert (independent work, saves a dispatch):
// Wt layout: [0]W1 [16384]Wg1 [32768]W2 [49152]Wg2 [65536]Wo, fragment-major:
//   elem ((nt*4+ks)*64+lane)*8+j = W[k][n], n = nt*16+(lane&15),
//   k = ks*32+(lane>>4)*8+j.

__global__ __launch_bounds__(256) void k_bhist_wcvt(
    const int* __restrict__ ei, int* __restrict__ bcnt, int E, int Et, int nbuck,
    const float* __restrict__ W1, const float* __restrict__ Wg1,
    const float* __restrict__ W2, const float* __restrict__ Wg2,
    const float* __restrict__ Wo, __half* __restrict__ Wt) {
    __shared__ int hist[256];
    int tid = threadIdx.x;
    if (tid < nbuck) hist[tid] = 0;
    __syncthreads();
    for (int e = blockIdx.x * 256 + tid; e < Et; e += gridDim.x * 256) {
        int d = (e < E) ? ei[E + e] : (e - E);
        atomicAdd(&hist[d >> 8], 1);
    }
    __syncthreads();
    if (tid < nbuck && hist[tid] > 0) atomicAdd(&bcnt[tid], hist[tid]);

    // weight convert: 73728 elems over 288 blocks x 256 threads exactly
    int i = blockIdx.x * 256 + tid;
    if (i < 65536) {
        int w = i >> 14;
        int j = i & 16383;
        int nt = j >> 11, ks = (j >> 9) & 3, lane = (j >> 3) & 63, jj = j & 7;
        int n = nt * 16 + (lane & 15);
        int k = ks * 32 + (lane >> 4) * 8 + jj;
        const float* W = (w == 0) ? W1 : (w == 1) ? Wg1 : (w == 2) ? W2 : Wg2;
        Wt[i] = __float2half(W[k * 128 + n]);
    } else if (i < 73728) {
        int j = i - 65536;                    // 8192: Wo is 128x64 -> NT=4
        int nt = j >> 11, ks = (j >> 9) & 3, lane = (j >> 3) & 63, jj = j & 7;
        int n = nt * 16 + (lane & 15);
        int k = ks * 32 + (lane >> 4) * 8 + jj;
        Wt[65536 + j] = __float2half(Wo[k * 64 + n]);
    }
}

__global__ void k_bscan(const int* __restrict__ bcnt, int* __restrict__ bbase,
                        int* __restrict__ bcur, int nbuck) {
    __shared__ int tmp[256];
    int tid = threadIdx.x;
    int v = (tid < nbuck) ? bcnt[tid] : 0;
    tmp[tid] = v;
    __syncthreads();
    for (int off = 1; off < 256; off <<= 1) {
        int t = (tid >= off) ? tmp[tid - off] : 0;
        __syncthreads();
        tmp[tid] += t;
        __syncthreads();
    }
    if (tid < nbuck) {
        int excl = tmp[tid] - v;
        bbase[tid] = excl;
        bcur[tid] = excl;
        if (tid == nbuck - 1) bbase[nbuck] = tmp[tid];
    }
}

__global__ __launch_bounds__(256) void k_bscatter(
    const int* __restrict__ ei, int* __restrict__ bcur,
    int2* __restrict__ ebuf, int E, int Et, int nbuck) {
    __shared__ int hist[256];
    __shared__ int base[256];
    __shared__ int off[256];
    constexpr int PT = CHUNK / 256;   // 16 edges per thread
    int tid = threadIdx.x;
    int cb = blockIdx.x * CHUNK;
    if (tid < nbuck) { hist[tid] = 0; off[tid] = 0; }
    __syncthreads();

    int sv[PT], dv[PT];
#pragma unroll
    for (int i = 0; i < PT; ++i) {
        int e = cb + i * 256 + tid;
        int s = 0, d = -1;
        if (e < Et) {
            if (e < E) { s = ei[e]; d = ei[E + e]; }
            else       { s = d = e - E; }
            atomicAdd(&hist[d >> 8], 1);
        }
        sv[i] = s; dv[i] = d;
    }
    __syncthreads();
    if (tid < nbuck && hist[tid] > 0)
        base[tid] = atomicAdd(&bcur[tid], hist[tid]);
    __syncthreads();
#pragma unroll
    for (int i = 0; i < PT; ++i) {
        if (dv[i] >= 0) {
            int b = dv[i] >> 8;
            int pos = base[b] + atomicAdd(&off[b], 1);
            ebuf[pos] = make_int2(sv[i], dv[i]);
        }
    }
}

__global__ __launch_bounds__(256) void k_csr(
    const int2* __restrict__ ebuf, const int* __restrict__ bbase,
    int* __restrict__ rowp, float* __restrict__ inv, int* __restrict__ esrc,
    int Nn, int Et) {
    __shared__ int hist[256];
    __shared__ int scan[256];
    __shared__ int cur[256];
    int tid = threadIdx.x;
    int b = blockIdx.x;
    int bb = bbase[b], cnt = bbase[b + 1] - bb;
    hist[tid] = 0;
    __syncthreads();
    for (int t = tid; t < cnt; t += 256)
        atomicAdd(&hist[ebuf[bb + t].y & 255], 1);
    __syncthreads();
    int v = hist[tid];
    scan[tid] = v;
    __syncthreads();
    for (int o = 1; o < 256; o <<= 1) {
        int t = (tid >= o) ? scan[tid - o] : 0;
        __syncthreads();
        scan[tid] += t;
        __syncthreads();
    }
    int excl = scan[tid] - v;
    int node = b * BK + tid;
    if (node < Nn) {
        rowp[node] = bb + excl;
        inv[node] = rsqrtf((float)v);
    }
    cur[tid] = excl;
    if (b == 0 && tid == 0) rowp[Nn] = Et;
    __syncthreads();
    for (int t = tid; t < cnt; t += 256) {
        int2 e = ebuf[bb + t];
        int pos = bb + atomicAdd(&cur[e.y & 255], 1);
        esrc[pos] = e.x;
    }
}

// ------------------------------ MFMA GEMM ----------------------------------
// out[M x NC] = A(M x 128, fp32 OR fp16) @ W(fp16, fragment-major Wt).
// 256 thr = 4 waves, one 16-row m-tile per wave -> 64 rows/block, 782 blocks.
// fp16 A is read directly (no cvt); fp32 A converted in-register (same RN
// rounding as storing fp16 -> bit-identical results either way).
// If asrc!=null, GAT alpha logits reduced from fp32 accumulators.

template <typename AT, int NC, typename OT>
__global__ __launch_bounds__(256) void gemm_mfma(
    const AT* __restrict__ A, const __half* __restrict__ Wt,
    const float* __restrict__ bias, OT* __restrict__ out,
    const float* __restrict__ asrc, const float* __restrict__ adst,
    float* __restrict__ alS, float* __restrict__ alD, int M) {
    constexpr int NT = NC / 16;
    __shared__ f16x8 Wl[NC * 16];             // NC*128 halfs, fragment-major
    const int tid = threadIdx.x;
    const int wv = tid >> 6, lane = tid & 63;
    const int m16 = lane & 15, quad = lane >> 4;

#pragma unroll
    for (int i = tid; i < NC * 16; i += 256)
        Wl[i] = ((const f16x8*)Wt)[i];
    __syncthreads();

    const int row0 = blockIdx.x * 64 + wv * 16;

    f16x8 af[4];
    {
        int row = row0 + m16;
        if (row > M - 1) row = M - 1;
        if constexpr (sizeof(AT) == 2) {
            const __half* ap = (const __half*)A + (size_t)row * 128 + quad * 8;
#pragma unroll
            for (int ks = 0; ks < 4; ++ks)
                af[ks] = *(const f16x8*)(ap + ks * 32);
        } else {
            const float* ap = (const float*)A + (size_t)row * 128 + quad * 8;
#pragma unroll
            for (int ks = 0; ks < 4; ++ks) {
                float4 lo = *(const float4*)(ap + ks * 32);
                float4 hi = *(const float4*)(ap + ks * 32 + 4);
                f16x8 v;
                v[0] = (_Float16)lo.x; v[1] = (_Float16)lo.y;
                v[2] = (_Float16)lo.z; v[3] = (_Float16)lo.w;
                v[4] = (_Float16)hi.x; v[5] = (_Float16)hi.y;
                v[6] = (_Float16)hi.z; v[7] = (_Float16)hi.w;
                af[ks] = v;
            }
        }
    }

    f32x4 acc[NT];
#pragma unroll
    for (int nt = 0; nt < NT; ++nt)
        acc[nt] = (f32x4){0.f, 0.f, 0.f, 0.f};

#pragma unroll
    for (int ks = 0; ks < 4; ++ks) {
#pragma unroll
        for (int nt = 0; nt < NT; ++nt) {
            f16x8 bf = Wl[(nt * 4 + ks) * 64 + lane];
            acc[nt] = __builtin_amdgcn_mfma_f32_16x16x32_f16(
                af[ks], bf, acc[nt], 0, 0, 0);
        }
    }

    // fused GAT alpha: s = xw.asrc, d = xw.adst per row (from fp32 accum)
    if (asrc) {
        float sa[NT], da[NT];
#pragma unroll
        for (int nt = 0; nt < NT; ++nt) {
            sa[nt] = asrc[nt * 16 + m16];
            da[nt] = adst[nt * 16 + m16];
        }
#pragma unroll
        for (int r = 0; r < 4; ++r) {
            float s = 0.f, d = 0.f;
#pragma unroll
            for (int nt = 0; nt < NT; ++nt) {
                s = fmaf(acc[nt][r], sa[nt], s);
                d = fmaf(acc[nt][r], da[nt], d);
            }
#pragma unroll
            for (int off = 8; off > 0; off >>= 1) {
                s += __shfl_xor(s, off);
                d += __shfl_xor(d, off);
            }
            int row = row0 + quad * 4 + r;
            if (m16 == 0 && row < M) { alS[row] = s; alD[row] = d; }
        }
    }

#pragma unroll
    for (int nt = 0; nt < NT; ++nt) {
#pragma unroll
        for (int r = 0; r < 4; ++r) {
            int row = row0 + quad * 4 + r;
            if (row < M) {
                float v = acc[nt][r];
                int col = nt * 16 + m16;
                if constexpr (sizeof(OT) == 2) {
                    ((__half*)out)[(size_t)row * NC + col] = __float2half(v);
                } else {
                    ((float*)out)[(size_t)row * NC + col] = v + bias[col];
                }
            }
        }
    }
}

// --------------------------- aggregation kernels ---------------------------
// R9-proven structure: one wave per destination node. lane = 16*g + q:
// quarter-wave g handles edge j+g of each group of 4; lane owns fp16 features
// 8q..8q+7 (16 B dwordx4). INVARIANT: lanes with index >= cnt hold wgt == 0
// and a valid sid (0 ok); all guards wave-uniform so shfl runs with full exec.
// Output templated: fp16 for intermediate h (layers 1-3; next GEMM rounded to
// fp16 anyway -> bit-identical), fp32 for the final h (required output).

__device__ __forceinline__ void gather_accum_h(
    const __half* __restrict__ xw, int q, int g, int cnt, int sid, float wgt,
    float acc[8]) {
    for (int base = 0; base < cnt; base += 32) {
        int c = cnt - base;           // wave-uniform
        float4 x[8];
        float w[8];
#pragma unroll
        for (int u = 0; u < 8; ++u) {
            if (u * 4 < c) {          // uniform guard
                int idx = base + 4 * u + g;
                int s = __shfl(sid, idx);
                w[u] = __shfl(wgt, idx);
                x[u] = *(const float4*)(xw + (size_t)s * 128 + q * 8);
            }
        }
#pragma unroll
        for (int u = 0; u < 8; ++u) {
            if (u * 4 < c) {          // uniform guard
                const __half2* h2 = (const __half2*)&x[u];
#pragma unroll
                for (int i = 0; i < 4; ++i) {
                    float2 cc = __half22float2(h2[i]);
                    acc[2 * i]     = fmaf(w[u], cc.x, acc[2 * i]);
                    acc[2 * i + 1] = fmaf(w[u], cc.y, acc[2 * i + 1]);
                }
            }
        }
    }
}

template <typename OT>
__device__ __forceinline__ void finish_store_q(
    float acc[8], const float* __restrict__ bias, OT* __restrict__ out,
    int n, int q, int g) {
#pragma unroll
    for (int i = 0; i < 8; ++i) {
        acc[i] += __shfl_xor(acc[i], 16);
        acc[i] += __shfl_xor(acc[i], 32);
    }
    if (g == 0) {
        float4 b0 = ((const float4*)bias)[q * 2];
        float4 b1 = ((const float4*)bias)[q * 2 + 1];
        float r[8];
        r[0] = fmaxf(acc[0] + b0.x, 0.f);
        r[1] = fmaxf(acc[1] + b0.y, 0.f);
        r[2] = fmaxf(acc[2] + b0.z, 0.f);
        r[3] = fmaxf(acc[3] + b0.w, 0.f);
        r[4] = fmaxf(acc[4] + b1.x, 0.f);
        r[5] = fmaxf(acc[5] + b1.y, 0.f);
        r[6] = fmaxf(acc[6] + b1.z, 0.f);
        r[7] = fmaxf(acc[7] + b1.w, 0.f);
        if constexpr (sizeof(OT) == 2) {
            f16x8 hv;
#pragma unroll
            for (int i = 0; i < 8; ++i) hv[i] = (_Float16)r[i];
            *(f16x8*)((__half*)out + (size_t)n * 128 + q * 8) = hv;
        } else {
            float4* orow = (float4*)((float*)out + (size_t)n * 128);
            orow[q * 2]     = make_float4(r[0], r[1], r[2], r[3]);
            orow[q * 2 + 1] = make_float4(r[4], r[5], r[6], r[7]);
        }
    }
}

template <typename OT>
__global__ __launch_bounds__(256) void k_gcn_agg(
    const __half* __restrict__ xw, const int* __restrict__ rowp,
    const int* __restrict__ esrc, const float* __restrict__ inv,
    const float* __restrict__ bias, OT* __restrict__ out, int Nn) {
    int gid = blockIdx.x * 256 + threadIdx.x;
    int n = gid >> 6, lane = gid & 63;
    if (n >= Nn) return;
    int q = lane & 15, g = lane >> 4;
    int beg = rowp[n], end = rowp[n + 1];
    float invd = inv[n];
    float acc[8] = {0.f, 0.f, 0.f, 0.f, 0.f, 0.f, 0.f, 0.f};
    for (int base = beg; base < end; base += WAVE) {
        int e = base + lane;
        bool valid = (e < end);
        int sid = valid ? esrc[e] : 0;
        float c = valid ? invd * inv[sid] : 0.f;
        gather_accum_h(xw, q, g, min(WAVE, end - base), sid, c, acc);
    }
    finish_store_q(acc, bias, out, n, q, g);
}

template <typename OT>
__global__ __launch_bounds__(256) void k_gat_agg(
    const __half* __restrict__ xw, const int* __restrict__ rowp,
    const int* __restrict__ esrc, const float* __restrict__ as_,
    const float* __restrict__ ad_, const float* __restrict__ bias,
    OT* __restrict__ out, int Nn) {
    int gid = blockIdx.x * 256 + threadIdx.x;
    int n = gid >> 6, lane = gid & 63;
    if (n >= Nn) return;
    int q = lane & 15, g = lane >> 4;
    int beg = rowp[n], end = rowp[n + 1];
    int deg = end - beg;
    float adn = ad_[n];
    float acc[8] = {0.f, 0.f, 0.f, 0.f, 0.f, 0.f, 0.f, 0.f};

    if (deg <= WAVE) {
        // fused path (deg<=64, ~all nodes): edge data loaded once, logit in reg
        bool valid = (lane < deg);
        int sid = 0;
        float v = -1e30f;
        if (valid) {
            sid = esrc[beg + lane];
            float t = as_[sid] + adn;
            v = (t > 0.f) ? t : 0.2f * t;
        }
        float m = v;
#pragma unroll
        for (int off = 32; off > 0; off >>= 1) m = fmaxf(m, __shfl_xor(m, off));
        float ex = valid ? __expf(v - m) : 0.f;
        float ssum = ex;
#pragma unroll
        for (int off = 32; off > 0; off >>= 1) ssum += __shfl_xor(ssum, off);
        float wgt = ex * (1.f / ssum);   // invalid lanes: 0
        gather_accum_h(xw, q, g, deg, sid, wgt, acc);
    } else {
        // generic two-pass path (deg>64: essentially never at E/N=16)
        float m = -1e30f, ssum = 0.f;
        for (int e = beg + lane; e < end; e += WAVE) {
            float v = as_[esrc[e]] + adn;
            v = (v > 0.f) ? v : 0.2f * v;
            float mn = fmaxf(m, v);
            ssum = ssum * __expf(m - mn) + __expf(v - mn);
            m = mn;
        }
#pragma unroll
        for (int off = 32; off > 0; off >>= 1) {
            float mo = __shfl_xor(m, off);
            float so = __shfl_xor(ssum, off);
            float mn = fmaxf(m, mo);
            ssum = ssum * __expf(m - mn) + so * __expf(mo - mn);
            m = mn;
        }
        float rden = 1.f / ssum;
        for (int base = beg; base < end; base += WAVE) {
            int e = base + lane;
            bool valid = (e < end);
            int sid = valid ? esrc[e] : 0;
            float wgt = 0.f;
            if (valid) {
                float v = as_[sid] + adn;
                v = (v > 0.f) ? v : 0.2f * v;
                wgt = __expf(v - m) * rden;
            }
            gather_accum_h(xw, q, g, min(WAVE, end - base), sid, wgt, acc);
        }
    }
    finish_store_q(acc, bias, out, n, q, g);
}

// ------------------------------- launch ------------------------------------

extern "C" void kernel_launch(void* const* d_in, const int* in_sizes, int n_in,
                              void* d_out, int out_size, void* d_ws, size_t ws_size,
                              hipStream_t stream) {
    const float* x   = (const float*)d_in[0];
    const int*   ei  = (const int*)d_in[1];
    const float* W1  = (const float*)d_in[2];
    const float* b1  = (const float*)d_in[3];
    const float* Wg1 = (const float*)d_in[4];
    const float* as1 = (const float*)d_in[5];
    const float* ad1 = (const float*)d_in[6];
    const float* bg1 = (const float*)d_in[7];
    const float* W2  = (const float*)d_in[8];
    const float* b2  = (const float*)d_in[9];
    const float* Wg2 = (const float*)d_in[10];
    const float* as2 = (const float*)d_in[11];
    const float* ad2 = (const float*)d_in[12];
    const float* bg2 = (const float*)d_in[13];
    const float* Wo  = (const float*)d_in[14];
    const float* bo  = (const float*)d_in[15];

    const int Nn = in_sizes[0] / 128;
    const int E  = in_sizes[1] / 2;
    const int Et = E + Nn;
    const int H  = 128;
    const int nbuck = (Nn + BK - 1) / BK;   // 196

    float* outH = (float*)d_out;
    float* outZ = outH + (size_t)Nn * H;

    char* p = (char*)d_ws;
    auto carve = [&](size_t bytes) {
        char* r = p;
        p += (bytes + 255) & ~(size_t)255;
        return r;
    };
    __half* bufA = (__half*)carve((size_t)Nn * H * sizeof(__half));  // xw fp16
    __half* bufB = (__half*)carve((size_t)Nn * H * sizeof(__half));  // h fp16
    __half* Wt   = (__half*)carve((size_t)73728 * sizeof(__half));   // fp16 W frags x5
    float* alS   = (float*)carve((size_t)Nn * sizeof(float));
    float* alD   = (float*)carve((size_t)Nn * sizeof(float));
    float* inv   = (float*)carve((size_t)Nn * sizeof(float));
    int*   rowp  = (int*)carve((size_t)(Nn + 1) * sizeof(int));
    int*   esrc  = (int*)carve((size_t)Et * sizeof(int));
    int2*  ebuf  = (int2*)carve((size_t)Et * sizeof(int2));
    int*   bcnt  = (int*)carve((size_t)nbuck * sizeof(int));
    int*   bbase = (int*)carve((size_t)(nbuck + 1) * sizeof(int));
    int*   bcur  = (int*)carve((size_t)nbuck * sizeof(int));
    (void)ws_size; (void)n_in; (void)out_size;

    const int aggBlocks = (Nn * WAVE + 255) / 256;   // 12500: 1 node/wave
    const int gemmB = (Nn + 63) / 64;                // 782
    const int scatB = (Et + CHUNK - 1) / CHUNK;      // 208

    // graph build (two-level bucket sort) + weight convert
    hipMemsetAsync(bcnt, 0, (size_t)nbuck * sizeof(int), stream);
    k_bhist_wcvt<<<288, 256, 0, stream>>>(ei, bcnt, E, Et, nbuck,
                                          W1, Wg1, W2, Wg2, Wo, Wt);
    k_bscan<<<1, 256, 0, stream>>>(bcnt, bbase, bcur, nbuck);
    k_bscatter<<<scatB, 256, 0, stream>>>(ei, bcur, ebuf, E, Et, nbuck);
    k_csr<<<nbuck, 256, 0, stream>>>(ebuf, bbase, rowp, inv, esrc, Nn, Et);

    // layer 1: GCN
    gemm_mfma<float, 128, __half><<<gemmB, 256, 0, stream>>>(
        x, Wt, nullptr, bufA, nullptr, nullptr, nullptr, nullptr, Nn);
    k_gcn_agg<__half><<<aggBlocks, 256, 0, stream>>>(
        bufA, rowp, esrc, inv, b1, bufB, Nn);

    // layer 2: GAT
    gemm_mfma<__half, 128, __half><<<gemmB, 256, 0, stream>>>(
        bufB, Wt + 16384, nullptr, bufA, as1, ad1, alS, alD, Nn);
    k_gat_agg<__half><<<aggBlocks, 256, 0, stream>>>(
        bufA, rowp, esrc, alS, alD, bg1, bufB, Nn);

    // layer 3: GCN
    gemm_mfma<__half, 128, __half><<<gemmB, 256, 0, stream>>>(
        bufB, Wt + 32768, nullptr, bufA, nullptr, nullptr, nullptr, nullptr, Nn);
    k_gcn_agg<__half><<<aggBlocks, 256, 0, stream>>>(
        bufA, rowp, esrc, inv, b2, bufB, Nn);

    // layer 4: GAT -> fp32 outH (required output h)
    gemm_mfma<__half, 128, __half><<<gemmB, 256, 0, stream>>>(
        bufB, Wt + 49152, nullptr, bufA, as2, ad2, alS, alD, Nn);
    k_gat_agg<float><<<aggBlocks, 256, 0, stream>>>(
        bufA, rowp, esrc, alS, alD, bg2, outH, Nn);

    // output layer: z = h @ Wo + bo
    gemm_mfma<float, 64, float><<<gemmB, 256, 0, stream>>>(
        outH, Wt + 65536, bo, outZ, nullptr, nullptr, nullptr, nullptr, Nn);
}